// Round 6
// baseline (105.030 us; speedup 1.0000x reference)
//
#include <hip/hip_runtime.h>
#include <math.h>

#define BB 4
#define NN 512
#define PP 2048
#define EE 32768
#define FH 128
#define DRBF 32
#define INDIM 416
#define CUT 4.0f
#define PI_F 3.14159265358979323846f
#define NMAX 8192
#define KS1 13            // 416 = 13 * 32

struct __align__(16) Rec { float dx, dy, dz; unsigned int ap; };

// ws layout: cnt@0 | recs@0x100 (128KB) | cwA@0x30000 | pA@0x38000 |
//            HT@0x40000 (416*NMAX*4 = 13.6MB) | accumA@0xE00000 (NMAX*128*4 = 4MB)

__global__ __launch_bounds__(256) void init_kernel(float* __restrict__ out,
                                                   float* __restrict__ accumA,
                                                   int* __restrict__ cnt) {
  int idx = blockIdx.x * blockDim.x + threadIdx.x;
  int stride = gridDim.x * blockDim.x;
  for (int i = idx; i < BB * PP; i += stride) out[i] = 0.0f;
  float4 z = make_float4(0.f, 0.f, 0.f, 0.f);
  for (int i = idx; i < NMAX * FH / 4; i += stride) ((float4*)accumA)[i] = z;
  if (idx == 0) *cnt = 0;
}

__global__ __launch_bounds__(256) void filter_kernel(
    const int* __restrict__ pe, const float* __restrict__ pdisp,
    const float* __restrict__ cell, const float* __restrict__ atom_xyz,
    const float* __restrict__ probe_xyz, int* __restrict__ cnt, Rec* __restrict__ recs) {
  int e = blockIdx.x * blockDim.x + threadIdx.x;   // grid covers exactly B*E
  int b = e >> 15;
  int2 ap = ((const int2*)pe)[e];
  float pd0 = pdisp[e*3], pd1 = pdisp[e*3+1], pd2 = pdisp[e*3+2];
  const float* cb = cell + b*9;
  float d0 = pd0*cb[0] + pd1*cb[3] + pd2*cb[6];
  float d1 = pd0*cb[1] + pd1*cb[4] + pd2*cb[7];
  float d2 = pd0*cb[2] + pd1*cb[5] + pd2*cb[8];
  int ag = b*NN + ap.x;
  int pg = b*PP + ap.y;
  float dx = probe_xyz[pg*3]   - (atom_xyz[ag*3]   + d0);
  float dy = probe_xyz[pg*3+1] - (atom_xyz[ag*3+1] + d1);
  float dz = probe_xyz[pg*3+2] - (atom_xyz[ag*3+2] + d2);
  float dist2 = dx*dx + dy*dy + dz*dz;
  if (dist2 < CUT*CUT) {
    int i = atomicAdd(cnt, 1);
    if (i < NMAX) {
      Rec r; r.dx = dx; r.dy = dy; r.dz = dz;
      r.ap = ((unsigned)ag << 16) | (unsigned)pg;
      recs[i] = r;
    }
  }
}

// Build HT[k][edge] (k-major, stride NMAX) + cwA/pA for surviving edges.
__global__ __launch_bounds__(256) void gather_kernel(
    const Rec* __restrict__ recs, const int* __restrict__ cnt,
    const float* __restrict__ S, const float* __restrict__ V,
    float* __restrict__ HT, float* __restrict__ cwA, int* __restrict__ pA) {
  __shared__ float hS[4][420];
  const int tid  = threadIdx.x;
  const int lane = tid & 63;
  const int wave = tid >> 6;
  int n = *cnt; if (n > NMAX) n = NMAX;
  const int bt = blockIdx.x;
  if (bt * 4 >= n) return;

  const int eg = bt * 4 + wave;
  Rec r;
  if (eg < n) r = recs[eg];
  else { r.dx = 1.0f; r.dy = 0.0f; r.dz = 0.0f; r.ap = 0u; }
  unsigned a = r.ap >> 16;
  const float2* Vf2 = (const float2*)V;
  const float2* Sf2 = (const float2*)S;
  float2 v0 = Vf2[(a*3+0)*64 + lane];
  float2 v1 = Vf2[(a*3+1)*64 + lane];
  float2 v2 = Vf2[(a*3+2)*64 + lane];
  float2 sj = Sf2[a*64 + lane];
  float d = sqrtf(r.dx*r.dx + r.dy*r.dy + r.dz*r.dz);
  float inv = 1.0f / (d + 1e-8f);
  float rh0 = r.dx*inv, rh1 = r.dy*inv, rh2 = r.dz*inv;
  if (lane < DRBF) hS[wave][lane] = sinf(d * (float)(lane+1) * (PI_F/CUT)) / d;
  float2 q;  q.x  = v0.x*rh0 + v1.x*rh1 + v2.x*rh2;
             q.y  = v0.y*rh0 + v1.y*rh1 + v2.y*rh2;
  float2 nv; nv.x = sqrtf(v0.x*v0.x + v1.x*v1.x + v2.x*v2.x);
             nv.y = sqrtf(v0.y*v0.y + v1.y*v1.y + v2.y*v2.y);
  *(float2*)&hS[wave][DRBF        + 2*lane] = q;
  *(float2*)&hS[wave][DRBF +   FH + 2*lane] = nv;
  *(float2*)&hS[wave][DRBF + 2*FH + 2*lane] = sj;
  if (lane == 0 && eg < n) {
    cwA[eg] = 0.5f * (cosf((PI_F/CUT) * d) + 1.0f);
    pA[eg]  = (int)(r.ap & 0xFFFFu);
  }
  __syncthreads();

  for (int i = tid; i < INDIM * 4; i += 256) {
    int k = i >> 2, e = i & 3;
    if (bt * 4 + e < n) HT[k * NMAX + bt * 4 + e] = hS[e][k];
  }
}

// Layer 1 as k-split tiled GEMM: block = (eb: 64 edges) x (128 feats) x (ks: 32 k's).
// Stage tiles in LDS (independent float4 loads), register-tile 4e x 8f per thread,
// partials atomically accumulated into accumA (zeroed by init).
__global__ __launch_bounds__(256) void mlp1_kernel(
    const float* __restrict__ HT, const int* __restrict__ cnt,
    const float* __restrict__ W1, float* __restrict__ accumA) {
  __shared__ float hT[32][64];    // 8KB  [k][e]
  __shared__ float wT[32][128];   // 16KB [k][f]
  int n = *cnt; if (n > NMAX) n = NMAX;
  const int eb = blockIdx.x / KS1;
  const int ks = blockIdx.x % KS1;
  if (eb * 64 >= n) return;
  const int e0 = eb * 64, k0 = ks * 32;
  const int t = threadIdx.x;

  #pragma unroll
  for (int rr = 0; rr < 2; ++rr) {          // h tile: 512 float4
    int idx = t + rr * 256;
    int kk = idx >> 4, e4 = idx & 15;
    *(float4*)&hT[kk][e4*4] = *(const float4*)&HT[(k0+kk)*NMAX + e0 + e4*4];
  }
  #pragma unroll
  for (int rr = 0; rr < 4; ++rr) {          // W tile: 1024 float4
    int idx = t + rr * 256;
    int kk = idx >> 5, f4 = idx & 31;
    *(float4*)&wT[kk][f4*4] = *(const float4*)&W1[(k0+kk)*FH + f4*4];
  }
  __syncthreads();

  const int e4 = t & 15;        // edges e0 + e4*4 .. +3
  const int f8 = t >> 4;        // feats f8*8 .. +7
  float acc[4][8];
  #pragma unroll
  for (int i = 0; i < 4; ++i)
    #pragma unroll
    for (int j = 0; j < 8; ++j) acc[i][j] = 0.0f;

  #pragma unroll
  for (int k = 0; k < 32; ++k) {
    float4 hv = *(const float4*)&hT[k][e4*4];
    float4 wa = *(const float4*)&wT[k][f8*8];
    float4 wb = *(const float4*)&wT[k][f8*8+4];
    float ha[4] = {hv.x, hv.y, hv.z, hv.w};
    float wv[8] = {wa.x, wa.y, wa.z, wa.w, wb.x, wb.y, wb.z, wb.w};
    #pragma unroll
    for (int i = 0; i < 4; ++i)
      #pragma unroll
      for (int j = 0; j < 8; ++j) acc[i][j] = fmaf(ha[i], wv[j], acc[i][j]);
  }

  #pragma unroll
  for (int i = 0; i < 4; ++i) {
    int ee = e0 + e4*4 + i;
    if (ee < n) {
      #pragma unroll
      for (int j = 0; j < 8; ++j)
        atomicAdd(&accumA[ee*FH + f8*8 + j], acc[i][j]);
    }
  }
}

// Layer 2 + layer 3 + cutoff + scatter. Block = 64 edges x 64 feats, K=128 in
// 4 staged rounds (T14: global loads issued before the barrier, silu+b1 fused
// into the h-stage). Per-edge dot with W3 reduced in-block, one atomic per edge.
__global__ __launch_bounds__(512) void mlp2_kernel(
    const float* __restrict__ accumA, const int* __restrict__ cnt,
    const float* __restrict__ b1, const float* __restrict__ W2,
    const float* __restrict__ b2, const float* __restrict__ W3,
    const float* __restrict__ b3, const float* __restrict__ cwA,
    const int* __restrict__ pA, float* __restrict__ out) {
  __shared__ float h2T[32][64];   // 8KB [k][e]
  __shared__ float w2T[32][64];   // 8KB [k][f]
  __shared__ float part[8][64];
  int n = *cnt; if (n > NMAX) n = NMAX;
  const int eb = blockIdx.x;
  if (eb * 64 >= n) return;
  const int e0 = eb * 64;
  const int t = threadIdx.x;
  const int e4 = t & 15;        // 4 edges
  const int f2 = t >> 4;        // 2 feats: f2*2, f2*2+1
  const int he = t >> 3, hj = t & 7;       // h-stage mapping
  const int wk = t >> 4, wf = t & 15;      // W-stage mapping

  float acc[4][2];
  #pragma unroll
  for (int i = 0; i < 4; ++i) { acc[i][0] = 0.0f; acc[i][1] = 0.0f; }

  #pragma unroll
  for (int rd = 0; rd < 4; ++rd) {
    const int k0 = rd * 32;
    // issue stage loads (in flight across the first barrier)
    float4 hz = *(const float4*)&accumA[(e0+he)*FH + k0 + hj*4];
    float4 bz = *(const float4*)&b1[k0 + hj*4];
    float4 wz = *(const float4*)&W2[(k0 + wk)*64 + wf*4];
    __syncthreads();   // previous round's compute done reading LDS
    {
      float z0 = hz.x + bz.x, z1 = hz.y + bz.y, z2 = hz.z + bz.z, z3 = hz.w + bz.w;
      h2T[hj*4+0][he] = z0 / (1.0f + __expf(-z0));
      h2T[hj*4+1][he] = z1 / (1.0f + __expf(-z1));
      h2T[hj*4+2][he] = z2 / (1.0f + __expf(-z2));
      h2T[hj*4+3][he] = z3 / (1.0f + __expf(-z3));
      *(float4*)&w2T[wk][wf*4] = wz;
    }
    __syncthreads();
    #pragma unroll
    for (int k = 0; k < 32; ++k) {
      float4 hv = *(const float4*)&h2T[k][e4*4];
      float2 wv = *(const float2*)&w2T[k][f2*2];
      float ha[4] = {hv.x, hv.y, hv.z, hv.w};
      #pragma unroll
      for (int i = 0; i < 4; ++i) {
        acc[i][0] = fmaf(ha[i], wv.x, acc[i][0]);
        acc[i][1] = fmaf(ha[i], wv.y, acc[i][1]);
      }
    }
  }

  // finish: silu + b2, dot W3, reduce across f2 groups
  float b2a = b2[f2*2], b2b = b2[f2*2+1];
  float w3a = W3[f2*2], w3b = W3[f2*2+1];
  float pe[4];
  #pragma unroll
  for (int i = 0; i < 4; ++i) {
    float za = acc[i][0] + b2a, zb = acc[i][1] + b2b;
    float sa = za / (1.0f + __expf(-za));
    float sb = zb / (1.0f + __expf(-zb));
    pe[i] = fmaf(sa, w3a, sb * w3b);
  }
  #pragma unroll
  for (int i = 0; i < 4; ++i) {
    pe[i] += __shfl_xor(pe[i], 16, 64);
    pe[i] += __shfl_xor(pe[i], 32, 64);
  }
  const int wv_ = t >> 6, lane = t & 63;
  if (lane < 16) {
    #pragma unroll
    for (int i = 0; i < 4; ++i) part[wv_][lane*4 + i] = pe[i];
  }
  __syncthreads();
  if (t < 64) {
    int e = e0 + t;
    if (e < n) {
      float s = b3[0];
      #pragma unroll
      for (int w = 0; w < 8; ++w) s += part[w][t];
      atomicAdd(&out[pA[e]], s * cwA[e]);
    }
  }
}

extern "C" void kernel_launch(void* const* d_in, const int* in_sizes, int n_in,
                              void* d_out, int out_size, void* d_ws, size_t ws_size,
                              hipStream_t stream) {
  const float* S         = (const float*)d_in[0];
  const float* V         = (const float*)d_in[1];
  const float* atom_xyz  = (const float*)d_in[2];
  const float* probe_xyz = (const float*)d_in[3];
  const float* cell      = (const float*)d_in[4];
  const float* pdisp     = (const float*)d_in[5];
  const float* W1        = (const float*)d_in[6];
  const float* b1        = (const float*)d_in[7];
  const float* W2        = (const float*)d_in[8];
  const float* b2        = (const float*)d_in[9];
  const float* W3        = (const float*)d_in[10];
  const float* b3        = (const float*)d_in[11];
  const int*   pe        = (const int*)d_in[12];
  float* out = (float*)d_out;

  char* ws = (char*)d_ws;
  int*   cnt    = (int*)ws;
  Rec*   recs   = (Rec*)(ws + 0x100);
  float* cwA    = (float*)(ws + 0x30000);
  int*   pA     = (int*)(ws + 0x38000);
  float* HT     = (float*)(ws + 0x40000);
  float* accumA = (float*)(ws + 0xE00000);

  init_kernel<<<512, 256, 0, stream>>>(out, accumA, cnt);
  filter_kernel<<<BB*EE/256, 256, 0, stream>>>(pe, pdisp, cell, atom_xyz, probe_xyz, cnt, recs);
  gather_kernel<<<NMAX/4, 256, 0, stream>>>(recs, cnt, S, V, HT, cwA, pA);
  mlp1_kernel<<<(NMAX/64)*KS1, 256, 0, stream>>>(HT, cnt, W1, accumA);
  mlp2_kernel<<<NMAX/64, 512, 0, stream>>>(accumA, cnt, b1, W2, b2, W3, b3, cwA, pA, out);
}

// Round 7
// 36.198 us; speedup vs baseline: 2.9016x; 2.9016x over previous
//
#include <hip/hip_runtime.h>
#include <math.h>

#define BB 4
#define NN 512
#define PP 2048
#define EE 32768
#define FH 128
#define DRBF 32
#define INDIM 416
#define CUT 4.0f
#define PI_F 3.14159265358979323846f
#define NMAX 8192
#define HP 424            // padded hS row (floats)
#define NE 4              // edges per block iteration

struct __align__(16) Rec { float dx, dy, dz; unsigned int ap; };

// Pass 1: compact survivors; also zero the output accumulator (out is only
// touched again by mlp_kernel, which runs after -> no ordering hazard).
__global__ __launch_bounds__(256) void filter_kernel(
    const int* __restrict__ pe, const float* __restrict__ pdisp,
    const float* __restrict__ cell, const float* __restrict__ atom_xyz,
    const float* __restrict__ probe_xyz, int* __restrict__ cnt,
    Rec* __restrict__ recs, float* __restrict__ out) {
  int e = blockIdx.x * blockDim.x + threadIdx.x;   // grid covers exactly B*E
  if (e < BB * PP) out[e] = 0.0f;
  int b = e >> 15;
  int2 ap = ((const int2*)pe)[e];
  float pd0 = pdisp[e*3], pd1 = pdisp[e*3+1], pd2 = pdisp[e*3+2];
  const float* cb = cell + b*9;
  float d0 = pd0*cb[0] + pd1*cb[3] + pd2*cb[6];
  float d1 = pd0*cb[1] + pd1*cb[4] + pd2*cb[7];
  float d2 = pd0*cb[2] + pd1*cb[5] + pd2*cb[8];
  int ag = b*NN + ap.x;
  int pg = b*PP + ap.y;
  float dx = probe_xyz[pg*3]   - (atom_xyz[ag*3]   + d0);
  float dy = probe_xyz[pg*3+1] - (atom_xyz[ag*3+1] + d1);
  float dz = probe_xyz[pg*3+2] - (atom_xyz[ag*3+2] + d2);
  float dist2 = dx*dx + dy*dy + dz*dz;
  if (dist2 < CUT*CUT) {
    int i = atomicAdd(cnt, 1);
    if (i < NMAX) {
      Rec r; r.dx = dx; r.dy = dy; r.dz = dz;
      r.ap = ((unsigned)ag << 16) | (unsigned)pg;
      recs[i] = r;
    }
  }
}

// Fused MLP. Block = 256 threads / 4 waves handles 4 edges per iteration.
// Weights: per-lane coalesced global loads, ping-pong 16-deep register
// buffers (#pragma unroll 1 on the pair loop prevents full-hoist spilling).
// h: LDS, read via wave-uniform broadcast float4 (conflict-free).
__global__ __launch_bounds__(256) void mlp_kernel(
    const Rec* __restrict__ recs, const int* __restrict__ cnt,
    const float* __restrict__ S, const float* __restrict__ V,
    const float* __restrict__ W1, const float* __restrict__ b1,
    const float* __restrict__ W2, const float* __restrict__ b2,
    const float* __restrict__ W3, const float* __restrict__ b3,
    float* __restrict__ out) {
  __shared__ float hS[NE][HP];        // 6.8 KB
  __shared__ float h2S[NE][FH + 4];   // 2.1 KB
  __shared__ float cwS[NE];
  __shared__ unsigned pS[NE];

  const int t    = threadIdx.x;
  const int lane = t & 63;
  const int wave = t >> 6;
  int n = *cnt; if (n > NMAX) n = NMAX;

  const float2* Vf2 = (const float2*)V;
  const float2* Sf2 = (const float2*)S;

  const int f1 = t & 127;     // layer1 output feature
  const int eh = t >> 7;      // layer1 edge-half (edges eh*2, eh*2+1)
  const float b1v = b1[f1];
  const float b2v = b2[lane];
  const float w3v = W3[lane];
  const float b3v = b3[0];

  for (int bt = blockIdx.x; bt * NE < n; bt += gridDim.x) {
    // ---------- gather: wave w builds edge w ----------
    {
      const int eg = bt * NE + wave;
      Rec r;
      if (eg < n) r = recs[eg];
      else { r.dx = 1.0f; r.dy = 0.0f; r.dz = 0.0f; r.ap = 0xFFFFFFFFu; }
      unsigned a = (r.ap == 0xFFFFFFFFu) ? 0u : (r.ap >> 16);
      float2 v0 = Vf2[(a*3+0)*64 + lane];
      float2 v1 = Vf2[(a*3+1)*64 + lane];
      float2 v2 = Vf2[(a*3+2)*64 + lane];
      float2 sj = Sf2[a*64 + lane];
      float d = sqrtf(r.dx*r.dx + r.dy*r.dy + r.dz*r.dz);
      float inv = 1.0f / (d + 1e-8f);
      float rh0 = r.dx*inv, rh1 = r.dy*inv, rh2 = r.dz*inv;
      if (lane < DRBF) hS[wave][lane] = sinf(d * (float)(lane+1) * (PI_F/CUT)) / d;
      float2 q;  q.x  = v0.x*rh0 + v1.x*rh1 + v2.x*rh2;
                 q.y  = v0.y*rh0 + v1.y*rh1 + v2.y*rh2;
      float2 nv; nv.x = sqrtf(v0.x*v0.x + v1.x*v1.x + v2.x*v2.x);
                 nv.y = sqrtf(v0.y*v0.y + v1.y*v1.y + v2.y*v2.y);
      *(float2*)&hS[wave][DRBF        + 2*lane] = q;
      *(float2*)&hS[wave][DRBF +   FH + 2*lane] = nv;
      *(float2*)&hS[wave][DRBF + 2*FH + 2*lane] = sj;
      if (lane == 0) {
        cwS[wave] = 0.5f * (cosf((PI_F/CUT) * d) + 1.0f);
        pS[wave]  = (r.ap == 0xFFFFFFFFu) ? 0xFFFFu : (r.ap & 0xFFFFu);
      }
    }
    __syncthreads();

    // ---------- layer 1: acc over 416 k's, 13 ping-pong pairs of 16 ----------
    {
      float acc0 = b1v, acc1 = b1v;
      const float* Wp = W1 + f1;
      const float* hp0 = &hS[eh*2 + 0][0];
      const float* hp1 = &hS[eh*2 + 1][0];
      float wA[16], wB[16];
      #pragma unroll
      for (int i = 0; i < 16; ++i) wA[i] = Wp[i*FH];

      #pragma unroll 1
      for (int pr = 0; pr < 13; ++pr) {
        const int kA = pr*32, kB = pr*32 + 16;
        #pragma unroll
        for (int i = 0; i < 16; ++i) wB[i] = Wp[(kB + i)*FH];
        #pragma unroll
        for (int q = 0; q < 4; ++q) {
          float4 h0 = *(const float4*)(hp0 + kA + q*4);
          float4 h1 = *(const float4*)(hp1 + kA + q*4);
          acc0 = fmaf(h0.x, wA[q*4+0], acc0); acc1 = fmaf(h1.x, wA[q*4+0], acc1);
          acc0 = fmaf(h0.y, wA[q*4+1], acc0); acc1 = fmaf(h1.y, wA[q*4+1], acc1);
          acc0 = fmaf(h0.z, wA[q*4+2], acc0); acc1 = fmaf(h1.z, wA[q*4+2], acc1);
          acc0 = fmaf(h0.w, wA[q*4+3], acc0); acc1 = fmaf(h1.w, wA[q*4+3], acc1);
        }
        if (pr < 12) {
          #pragma unroll
          for (int i = 0; i < 16; ++i) wA[i] = Wp[(kA + 32 + i)*FH];
        }
        #pragma unroll
        for (int q = 0; q < 4; ++q) {
          float4 h0 = *(const float4*)(hp0 + kB + q*4);
          float4 h1 = *(const float4*)(hp1 + kB + q*4);
          acc0 = fmaf(h0.x, wB[q*4+0], acc0); acc1 = fmaf(h1.x, wB[q*4+0], acc1);
          acc0 = fmaf(h0.y, wB[q*4+1], acc0); acc1 = fmaf(h1.y, wB[q*4+1], acc1);
          acc0 = fmaf(h0.z, wB[q*4+2], acc0); acc1 = fmaf(h1.z, wB[q*4+2], acc1);
          acc0 = fmaf(h0.w, wB[q*4+3], acc0); acc1 = fmaf(h1.w, wB[q*4+3], acc1);
        }
      }
      h2S[eh*2 + 0][f1] = acc0 / (1.0f + __expf(-acc0));
      h2S[eh*2 + 1][f1] = acc1 / (1.0f + __expf(-acc1));
    }
    __syncthreads();

    // ---------- layer 2: wave = edge, lane = feature; 4 ping-pong pairs ----------
    float acc2 = b2v;
    {
      const float* Wp = W2 + lane;
      const float* hp = &h2S[wave][0];
      float wA[16], wB[16];
      #pragma unroll
      for (int i = 0; i < 16; ++i) wA[i] = Wp[i*64];

      #pragma unroll 1
      for (int pr = 0; pr < 4; ++pr) {
        const int kA = pr*32, kB = pr*32 + 16;
        #pragma unroll
        for (int i = 0; i < 16; ++i) wB[i] = Wp[(kB + i)*64];
        #pragma unroll
        for (int q = 0; q < 4; ++q) {
          float4 hv = *(const float4*)(hp + kA + q*4);
          acc2 = fmaf(hv.x, wA[q*4+0], acc2);
          acc2 = fmaf(hv.y, wA[q*4+1], acc2);
          acc2 = fmaf(hv.z, wA[q*4+2], acc2);
          acc2 = fmaf(hv.w, wA[q*4+3], acc2);
        }
        if (pr < 3) {
          #pragma unroll
          for (int i = 0; i < 16; ++i) wA[i] = Wp[(kA + 32 + i)*64];
        }
        #pragma unroll
        for (int q = 0; q < 4; ++q) {
          float4 hv = *(const float4*)(hp + kB + q*4);
          acc2 = fmaf(hv.x, wB[q*4+0], acc2);
          acc2 = fmaf(hv.y, wB[q*4+1], acc2);
          acc2 = fmaf(hv.z, wB[q*4+2], acc2);
          acc2 = fmaf(hv.w, wB[q*4+3], acc2);
        }
      }
    }

    // ---------- layer 3: silu, dot with W3 across 64 lanes, scatter ----------
    {
      float h2 = acc2 / (1.0f + __expf(-acc2));
      float rs = h2 * w3v;
      #pragma unroll
      for (int off = 32; off; off >>= 1) rs += __shfl_xor(rs, off, 64);
      if (lane == 0) {
        unsigned p = pS[wave];
        if (p != 0xFFFFu) atomicAdd(&out[p], (rs + b3v) * cwS[wave]);
      }
    }
    __syncthreads();   // protect hS/h2S before next iteration overwrites
  }
}

extern "C" void kernel_launch(void* const* d_in, const int* in_sizes, int n_in,
                              void* d_out, int out_size, void* d_ws, size_t ws_size,
                              hipStream_t stream) {
  const float* S         = (const float*)d_in[0];
  const float* V         = (const float*)d_in[1];
  const float* atom_xyz  = (const float*)d_in[2];
  const float* probe_xyz = (const float*)d_in[3];
  const float* cell      = (const float*)d_in[4];
  const float* pdisp     = (const float*)d_in[5];
  const float* W1        = (const float*)d_in[6];
  const float* b1        = (const float*)d_in[7];
  const float* W2        = (const float*)d_in[8];
  const float* b2        = (const float*)d_in[9];
  const float* W3        = (const float*)d_in[10];
  const float* b3        = (const float*)d_in[11];
  const int*   pe        = (const int*)d_in[12];
  float* out = (float*)d_out;

  int* cnt  = (int*)d_ws;
  Rec* recs = (Rec*)((char*)d_ws + 256);

  hipMemsetAsync(cnt, 0, 4, stream);
  filter_kernel<<<BB*EE/256, 256, 0, stream>>>(pe, pdisp, cell, atom_xyz, probe_xyz,
                                               cnt, recs, out);
  mlp_kernel<<<384, 256, 0, stream>>>(recs, cnt, S, V, W1, b1, W2, b2, W3, b3, out);
}